// Round 1
// baseline (601.317 us; speedup 1.0000x reference)
//
#include <hip/hip_runtime.h>
#include <hip/hip_bf16.h>

// MatchNet: MLP -> batched PDHG LP solve.
// B=2048 rows; m=128 (combos), n=512 (structures); 60 PDHG iters; CONTROL=10.
// One workgroup of 512 threads per batch row. Sparse S handled via
// CSR (row lists, for xb @ S^T) and CSC (col lists, for lam1 @ S) built by a
// one-block prep kernel that also runs the 30-step power iteration for L.

#define N_COMBOS   128
#define N_STRUCTS  512
#define BATCH      2048
#define HID        20
#define N_ITERS    60
#define ROWCAP     48   // max nnz per row of S (mean ~16); overflow prob ~1e-10
#define COLCAP     24   // max nnz per col of S (mean ~4);  overflow prob ~1e-10

// ---------------- workspace layout (bytes) ----------------
// 0     : float tau (= sig = 0.9/L)
// 64    : int   col_cnt[512]              (2048 B)
// 2112  : u8    col_idx[512*COLCAP]       (12288 B)
// 14400 : int   row_cnt[128]              (512 B)
// 14912 : u16   row_idx[128*ROWCAP]       (12288 B)
// total ~27.2 KB

__global__ __launch_bounds__(512) void prep_kernel(
    const float* __restrict__ S,
    float* __restrict__ tau_ws,
    int* __restrict__ col_cnt_g, unsigned char* __restrict__ col_idx_g,
    int* __restrict__ row_cnt_g, unsigned short* __restrict__ row_idx_g)
{
    __shared__ int            col_cnt_s[N_STRUCTS];
    __shared__ unsigned char  col_idx_s[N_STRUCTS * COLCAP];
    __shared__ int            row_cnt_s[N_COMBOS];
    __shared__ unsigned short row_idx_s[N_COMBOS * ROWCAP];
    __shared__ float v[N_STRUCTS];
    __shared__ float sv[N_COMBOS];
    __shared__ float red[8];

    const int t = threadIdx.x;

    // ---- build CSC (column lists: rows i where S[i][j] != 0) ----
    {
        int c = 0;
        for (int i = 0; i < N_COMBOS; ++i) {
            if (S[i * N_STRUCTS + t] != 0.0f) {
                if (c < COLCAP) col_idx_s[t * COLCAP + c] = (unsigned char)i;
                ++c;
            }
        }
        if (c > COLCAP) c = COLCAP;
        col_cnt_s[t] = c;
        col_cnt_g[t] = c;
        for (int k = 0; k < COLCAP; ++k)
            col_idx_g[t * COLCAP + k] = (k < c) ? col_idx_s[t * COLCAP + k] : (unsigned char)0;
    }
    // ---- build CSR (row lists: cols j where S[i][j] != 0) ----
    if (t < N_COMBOS) {
        int c = 0;
        for (int j = 0; j < N_STRUCTS; ++j) {
            if (S[t * N_STRUCTS + j] != 0.0f) {
                if (c < ROWCAP) row_idx_s[t * ROWCAP + c] = (unsigned short)j;
                ++c;
            }
        }
        if (c > ROWCAP) c = ROWCAP;
        row_cnt_s[t] = c;
        row_cnt_g[t] = c;
        for (int k = 0; k < ROWCAP; ++k)
            row_idx_g[t * ROWCAP + k] = (k < c) ? row_idx_s[t * ROWCAP + k] : (unsigned short)0;
    }

    v[t] = 1.0f;
    __syncthreads();

    // ---- power iteration: 30 normalize steps, then quadratic form ----
    for (int it = 0; it <= 30; ++it) {
        if (t < N_COMBOS) {
            float s = 0.0f;
            const int c = row_cnt_s[t];
            for (int k = 0; k < c; ++k) s += v[row_idx_s[t * ROWCAP + k]];
            sv[t] = s;
        }
        __syncthreads();
        float u;
        {
            float s = 0.0f;
            const int c = col_cnt_s[t];
            for (int k = 0; k < c; ++k) s += sv[col_idx_s[t * COLCAP + k]];
            u = s + v[t];                       // (S^T S + I) v
        }
        float p = (it < 30) ? u * u : u * v[t]; // ||u||^2  or  v . u
        for (int off = 32; off; off >>= 1) p += __shfl_xor(p, off);
        if ((t & 63) == 0) red[t >> 6] = p;
        __syncthreads();
        const float tot = red[0] + red[1] + red[2] + red[3] +
                          red[4] + red[5] + red[6] + red[7];
        if (it < 30) {
            const float nrm = sqrtf(tot);
            v[t] = u / nrm;
            __syncthreads();
        } else {
            if (t == 0) tau_ws[0] = 0.9f / sqrtf(tot);   // tau = sig = 0.9/L
        }
    }
}

__global__ __launch_bounds__(512) void solve_kernel(
    const float* __restrict__ X,
    const float* __restrict__ W1, const float* __restrict__ b1,
    const float* __restrict__ W2, const float* __restrict__ b2,
    const float* __restrict__ W3, const float* __restrict__ b3,
    const float* __restrict__ W4, const float* __restrict__ b4,
    const float* __restrict__ tau_ws,
    const int* __restrict__ col_cnt_g, const unsigned char* __restrict__ col_idx_g,
    const int* __restrict__ row_cnt_g, const unsigned short* __restrict__ row_idx_g,
    float* __restrict__ out)
{
    __shared__ float b_lds[N_COMBOS];
    __shared__ float xb_lds[N_STRUCTS];
    __shared__ float lam1_lds[N_COMBOS];
    __shared__ float red[8];
    __shared__ float ha[HID], hb[HID];
    __shared__ alignas(16) int            col_cnt_s[N_STRUCTS];
    __shared__ alignas(16) unsigned char  col_idx_s[N_STRUCTS * COLCAP];
    __shared__ alignas(16) int            row_cnt_s[N_COMBOS];
    __shared__ alignas(16) unsigned short row_idx_s[N_COMBOS * ROWCAP];

    const int t   = threadIdx.x;
    const int row = blockIdx.x;

    // ---- stage sparse index lists into LDS (16B vector copies) ----
    col_cnt_s[t] = col_cnt_g[t];
    if (t < N_COMBOS) row_cnt_s[t] = row_cnt_g[t];
    {
        const uint4* g1 = (const uint4*)col_idx_g;  uint4* l1 = (uint4*)col_idx_s;
        for (int i = t; i < (N_STRUCTS * COLCAP) / 16; i += 512) l1[i] = g1[i];
        const uint4* g2 = (const uint4*)row_idx_g;  uint4* l2 = (uint4*)row_idx_s;
        for (int i = t; i < (N_COMBOS * ROWCAP * 2) / 16; i += 512) l2[i] = g2[i];
    }

    float b_reg = 0.0f;                 // LP rhs b = Xf (threads 0..127 own it)
    if (t < N_COMBOS) { b_reg = X[row * N_COMBOS + t]; b_lds[t] = b_reg; }
    __syncthreads();

    // ---- MLP: z = tanh-chain(Xf) ----
    if (t < HID) {
        float s = b1[t];
        for (int k = 0; k < N_COMBOS; ++k) s = fmaf(b_lds[k], W1[k * HID + t], s);
        ha[t] = tanhf(s);
    }
    __syncthreads();
    if (t < HID) {
        float s = b2[t];
        for (int k = 0; k < HID; ++k) s = fmaf(ha[k], W2[k * HID + t], s);
        hb[t] = tanhf(s);
    }
    __syncthreads();
    if (t < HID) {
        float s = b3[t];
        for (int k = 0; k < HID; ++k) s = fmaf(hb[k], W3[k * HID + t], s);
        ha[t] = tanhf(s);
    }
    __syncthreads();
    float z = b4[t];
    for (int h = 0; h < HID; ++h) z = fmaf(ha[h], W4[h * N_STRUCTS + t], z);

    const float tau = tau_ws[0];
    const float sig = tau;

    // ---- PDHG ----
    float x   = fmaxf(z, 0.0f);
    float xb  = x;
    float lam1 = 0.0f;                  // dual for S x <= b (threads < 128)
    float lam2 = 0.0f;                  // dual for x >= 0

    const int my_cc = col_cnt_s[t];
    const int my_rc = (t < N_COMBOS) ? row_cnt_s[t] : 0;

    for (int it = 0; it < N_ITERS; ++it) {
        xb_lds[t] = xb;
        __syncthreads();                                   // A: xb ready
        if (t < N_COMBOS) {
            float s = 0.0f;
            for (int k = 0; k < my_rc; ++k) s += xb_lds[row_idx_s[t * ROWCAP + k]];
            const float u1 = lam1 + sig * s;               // lam1 + sig*(xb S^T)
            lam1 = fmaxf(u1 - sig * b_reg, 0.0f);
            lam1_lds[t] = lam1;
        }
        lam2 = fminf(lam2 + sig * xb, 0.0f);
        __syncthreads();                                   // B: lam1 ready
        float s2 = 0.0f;
        for (int k = 0; k < my_cc; ++k) s2 += lam1_lds[col_idx_s[t * COLCAP + k]];
        const float v = x - tau * (s2 + lam2);             // x - tau*(lam1 S + lam2)
        const float u = v + tau - z;                       // + tau*w - z, w = 1
        float p = u * u;
        for (int off = 32; off; off >>= 1) p += __shfl_xor(p, off);
        if ((t & 63) == 0) red[t >> 6] = p;
        __syncthreads();                                   // C: norm partials ready
        const float nrm = sqrtf(red[0] + red[1] + red[2] + red[3] +
                                red[4] + red[5] + red[6] + red[7]);
        const float scale = fmaxf(0.0f, 1.0f - tau * 10.0f / fmaxf(nrm, 1e-12f));
        const float xn = z + scale * u;
        xb = 2.0f * xn - x;
        x  = xn;
    }

    out[row * N_STRUCTS + t] = x;
}

extern "C" void kernel_launch(void* const* d_in, const int* in_sizes, int n_in,
                              void* d_out, int out_size, void* d_ws, size_t ws_size,
                              hipStream_t stream)
{
    const float* X  = (const float*)d_in[0];
    const float* W1 = (const float*)d_in[1];
    const float* b1 = (const float*)d_in[2];
    const float* W2 = (const float*)d_in[3];
    const float* b2 = (const float*)d_in[4];
    const float* W3 = (const float*)d_in[5];
    const float* b3 = (const float*)d_in[6];
    const float* W4 = (const float*)d_in[7];
    const float* b4 = (const float*)d_in[8];
    const float* S  = (const float*)d_in[9];
    float* out = (float*)d_out;

    char* ws = (char*)d_ws;
    float*          tau_ws    = (float*)(ws + 0);
    int*            col_cnt_g = (int*)(ws + 64);
    unsigned char*  col_idx_g = (unsigned char*)(ws + 64 + 2048);
    int*            row_cnt_g = (int*)(ws + 64 + 2048 + 12288);
    unsigned short* row_idx_g = (unsigned short*)(ws + 64 + 2048 + 12288 + 512);

    prep_kernel<<<1, 512, 0, stream>>>(S, tau_ws, col_cnt_g, col_idx_g,
                                       row_cnt_g, row_idx_g);
    solve_kernel<<<BATCH, 512, 0, stream>>>(X, W1, b1, W2, b2, W3, b3, W4, b4,
                                            tau_ws, col_cnt_g, col_idx_g,
                                            row_cnt_g, row_idx_g, out);
}

// Round 2
// 415.769 us; speedup vs baseline: 1.4463x; 1.4463x over previous
//
#include <hip/hip_runtime.h>
#include <hip/hip_bf16.h>

// MatchNet: MLP -> batched PDHG LP solve.
// B=2048 rows; m=128 (combos), n=512 (structures); 60 PDHG iters; CONTROL=10.
// One workgroup of 512 threads per batch row.
// Sparse S as padded, sorted index lists (built by a 1-block prep kernel that
// also runs the 30-step power iteration for L). Gather indices packed 4/word;
// wave reductions via DPP (VALU) instead of DS shuffles.

#define N_COMBOS   128
#define N_STRUCTS  512
#define BATCH      2048
#define HID        20
#define N_ITERS    60
#define COLCAP     24   // max real nnz per col (mean ~4)
#define ROWCAP     48   // max real nnz per row (mean ~16)
#define COLSTRIDE  28   // u8 entries per col list (bank-friendly: 7 banks/thread-step)
#define ROWSTRIDE  52   // u16 entries per row list (odd u64-bank stride)

// ---------------- workspace layout (bytes) ----------------
// 0     : float tau (= sig = 0.9/L)
// 64    : int col_cnt4[512]                (2048 B)   padded counts (mult of 4)
// 2112  : u8  col_idx[512*28]              (14336 B)  raw idx 0..131 (128..131 dummy)
// 16448 : int row_cnt4[128]                (512 B)
// 16960 : u16 row_off[128*52]              (13312 B)  byte offsets idx*4 (2048.. dummy)

__device__ __forceinline__ float wave_sum_bcast(float x) {
#if __has_builtin(__builtin_amdgcn_update_dpp)
    float s = x;
    s += __builtin_bit_cast(float, __builtin_amdgcn_update_dpp(0, __builtin_bit_cast(int, s), 0x111, 0xf, 0xf, true)); // row_shr:1
    s += __builtin_bit_cast(float, __builtin_amdgcn_update_dpp(0, __builtin_bit_cast(int, s), 0x112, 0xf, 0xf, true)); // row_shr:2
    s += __builtin_bit_cast(float, __builtin_amdgcn_update_dpp(0, __builtin_bit_cast(int, s), 0x114, 0xf, 0xf, true)); // row_shr:4
    s += __builtin_bit_cast(float, __builtin_amdgcn_update_dpp(0, __builtin_bit_cast(int, s), 0x118, 0xf, 0xf, true)); // row_shr:8
    s += __builtin_bit_cast(float, __builtin_amdgcn_update_dpp(0, __builtin_bit_cast(int, s), 0x142, 0xa, 0xf, true)); // row_bcast:15
    s += __builtin_bit_cast(float, __builtin_amdgcn_update_dpp(0, __builtin_bit_cast(int, s), 0x143, 0xc, 0xf, true)); // row_bcast:31
    return __builtin_bit_cast(float, __builtin_amdgcn_readlane(__builtin_bit_cast(int, s), 63));
#else
    for (int off = 32; off; off >>= 1) x += __shfl_xor(x, off);
    return x;
#endif
}

__global__ __launch_bounds__(512) void prep_kernel(
    const float* __restrict__ S,
    float* __restrict__ tau_ws,
    int* __restrict__ col_cnt_g, unsigned char* __restrict__ col_idx_g,
    int* __restrict__ row_cnt_g, unsigned short* __restrict__ row_off_g)
{
    __shared__ int            row_cnt_s[N_COMBOS];
    __shared__ int            row_cnt4_s[N_COMBOS];
    __shared__ alignas(16) unsigned short row_lst[N_COMBOS * ROWSTRIDE];
    __shared__ alignas(16) unsigned char  col_idx_s[N_STRUCTS * COLSTRIDE];
    __shared__ int            col_cnt_s[N_STRUCTS];
    __shared__ alignas(16) float v_lds[N_STRUCTS + 4];
    __shared__ alignas(16) float sv_lds[N_COMBOS + 4];
    __shared__ alignas(16) float red[8];

    const int t = threadIdx.x;
    if (t < N_COMBOS) row_cnt_s[t] = 0;
    if (t < 4) { v_lds[N_STRUCTS + t] = 0.0f; sv_lds[N_COMBOS + t] = 0.0f; }
    __syncthreads();

    // ---- scan column t (coalesced across threads); append to row lists ----
    {
        int cc = 0;
        for (int i = 0; i < N_COMBOS; ++i) {
            if (S[i * N_STRUCTS + t] != 0.0f) {
                if (cc < COLCAP) col_idx_s[t * COLSTRIDE + cc] = (unsigned char)i;
                ++cc;
                int slot = atomicAdd(&row_cnt_s[i], 1);
                if (slot < ROWCAP) row_lst[i * ROWSTRIDE + slot] = (unsigned short)t;
            }
        }
        if (cc > COLCAP) cc = COLCAP;
        int cc4 = (cc + 3) & ~3;
        for (int k = cc; k < COLSTRIDE; ++k)
            col_idx_s[t * COLSTRIDE + k] = (unsigned char)(N_COMBOS + (k & 3));
        col_cnt_s[t] = cc4;
    }
    __syncthreads();

    // ---- sort row lists (ascending = reference fp32 sum order), pad, scale ----
    if (t < N_COMBOS) {
        int c = row_cnt_s[t]; if (c > ROWCAP) c = ROWCAP;
        unsigned short* L = &row_lst[t * ROWSTRIDE];
        for (int a = 1; a < c; ++a) {
            unsigned short key = L[a]; int b = a - 1;
            while (b >= 0 && L[b] > key) { L[b + 1] = L[b]; --b; }
            L[b + 1] = key;
        }
        int c4 = (c + 3) & ~3;
        for (int k = 0; k < c; ++k) L[k] = (unsigned short)(L[k] * 4);
        for (int k = c; k < ROWSTRIDE; ++k)
            L[k] = (unsigned short)((N_STRUCTS + (k & 3)) * 4);
        row_cnt4_s[t] = c4;
    }
    v_lds[t] = 1.0f;
    __syncthreads();

    // ---- power iteration: 30 normalize steps, then quadratic form ----
    const int my_cc = col_cnt_s[t];
    const int my_rc = (t < N_COMBOS) ? row_cnt4_s[t] : 0;
    for (int it = 0; it <= 30; ++it) {
        if (t < N_COMBOS) {
            float s = 0.0f;
            const unsigned short* rp = &row_lst[t * ROWSTRIDE];
            for (int k = 0; k < my_rc; k += 4) {
                unsigned long long w = *(const unsigned long long*)(rp + k);
                s += *(const float*)((const char*)v_lds + (w & 0xffffULL));
                s += *(const float*)((const char*)v_lds + ((w >> 16) & 0xffffULL));
                s += *(const float*)((const char*)v_lds + ((w >> 32) & 0xffffULL));
                s += *(const float*)((const char*)v_lds + (w >> 48));
            }
            sv_lds[t] = s;
        }
        __syncthreads();
        float u;
        {
            float s = 0.0f;
            const unsigned char* cp = &col_idx_s[t * COLSTRIDE];
            for (int k = 0; k < my_cc; k += 4) {
                unsigned int w = *(const unsigned int*)(cp + k);
                s += sv_lds[w & 255];
                s += sv_lds[(w >> 8) & 255];
                s += sv_lds[(w >> 16) & 255];
                s += sv_lds[w >> 24];
            }
            u = s + v_lds[t];                    // (S^T S + I) v
        }
        float p = (it < 30) ? u * u : u * v_lds[t];
        p = wave_sum_bcast(p);
        if ((t & 63) == 0) red[t >> 6] = p;
        __syncthreads();
        const float4 r0 = *(const float4*)red;
        const float4 r1 = *(const float4*)(red + 4);
        const float tot = r0.x + r0.y + r0.z + r0.w + r1.x + r1.y + r1.z + r1.w;
        if (it < 30) {
            const float nrm = sqrtf(tot);
            v_lds[t] = u / nrm;
            __syncthreads();
        } else {
            if (t == 0) tau_ws[0] = 0.9f / sqrtf(tot);
        }
    }

    // ---- export ----
    col_cnt_g[t] = col_cnt_s[t];
    {
        unsigned int* dst = (unsigned int*)col_idx_g;
        for (int k2 = 0; k2 < COLSTRIDE / 4; ++k2)
            dst[t * (COLSTRIDE / 4) + k2] = *(const unsigned int*)&col_idx_s[t * COLSTRIDE + k2 * 4];
    }
    if (t < N_COMBOS) {
        row_cnt_g[t] = row_cnt4_s[t];
        unsigned int* dst = (unsigned int*)row_off_g;
        for (int k2 = 0; k2 < ROWSTRIDE / 2; ++k2)
            dst[t * (ROWSTRIDE / 2) + k2] = *(const unsigned int*)&row_lst[t * ROWSTRIDE + k2 * 2];
    }
}

__global__ __launch_bounds__(512) void solve_kernel(
    const float* __restrict__ X,
    const float* __restrict__ W1, const float* __restrict__ b1,
    const float* __restrict__ W2, const float* __restrict__ b2,
    const float* __restrict__ W3, const float* __restrict__ b3,
    const float* __restrict__ W4, const float* __restrict__ b4,
    const float* __restrict__ tau_ws,
    const int* __restrict__ col_cnt_g, const unsigned char* __restrict__ col_idx_g,
    const int* __restrict__ row_cnt_g, const unsigned short* __restrict__ row_off_g,
    float* __restrict__ out)
{
    __shared__ float b_lds[N_COMBOS];
    __shared__ alignas(16) float xb_lds[N_STRUCTS + 4];
    __shared__ alignas(16) float lam1_lds[N_COMBOS + 4];
    __shared__ alignas(16) float red[8];
    __shared__ float ha[HID], hb[HID];
    __shared__ alignas(16) unsigned char  col_idx_s[N_STRUCTS * COLSTRIDE];
    __shared__ alignas(16) unsigned short row_off_s[N_COMBOS * ROWSTRIDE];
    __shared__ int col_cnt_s[N_STRUCTS];
    __shared__ int row_cnt_s[N_COMBOS];

    const int t   = threadIdx.x;
    const int row = blockIdx.x;

    // ---- stage index lists into LDS (16B vector copies) ----
    col_cnt_s[t] = col_cnt_g[t];
    if (t < N_COMBOS) row_cnt_s[t] = row_cnt_g[t];
    {
        const uint4* g1 = (const uint4*)col_idx_g;  uint4* l1 = (uint4*)col_idx_s;
        for (int i = t; i < (N_STRUCTS * COLSTRIDE) / 16; i += 512) l1[i] = g1[i];
        const uint4* g2 = (const uint4*)row_off_g;  uint4* l2 = (uint4*)row_off_s;
        for (int i = t; i < (N_COMBOS * ROWSTRIDE * 2) / 16; i += 512) l2[i] = g2[i];
    }
    if (t < 4) { xb_lds[N_STRUCTS + t] = 0.0f; lam1_lds[N_COMBOS + t] = 0.0f; }

    float b_reg = 0.0f;                 // LP rhs b = Xf (threads 0..127 own it)
    if (t < N_COMBOS) { b_reg = X[row * N_COMBOS + t]; b_lds[t] = b_reg; }
    __syncthreads();

    // ---- MLP: z = tanh-chain(Xf) ----
    if (t < HID) {
        float s = b1[t];
        for (int k = 0; k < N_COMBOS; ++k) s = fmaf(b_lds[k], W1[k * HID + t], s);
        ha[t] = tanhf(s);
    }
    __syncthreads();
    if (t < HID) {
        float s = b2[t];
        for (int k = 0; k < HID; ++k) s = fmaf(ha[k], W2[k * HID + t], s);
        hb[t] = tanhf(s);
    }
    __syncthreads();
    if (t < HID) {
        float s = b3[t];
        for (int k = 0; k < HID; ++k) s = fmaf(hb[k], W3[k * HID + t], s);
        ha[t] = tanhf(s);
    }
    __syncthreads();
    float z = b4[t];
    for (int h = 0; h < HID; ++h) z = fmaf(ha[h], W4[h * N_STRUCTS + t], z);

    const float tau = tau_ws[0];
    const float sig = tau;

    // ---- PDHG ----
    float x    = fmaxf(z, 0.0f);
    float xb   = x;
    float lam1 = 0.0f;                  // dual for S x <= b (threads < 128)
    float lam2 = 0.0f;                  // dual for x >= 0

    const int my_cc = col_cnt_s[t];
    const int my_rc = (t < N_COMBOS) ? row_cnt_s[t] : 0;
    const unsigned char*  cp = &col_idx_s[t * COLSTRIDE];
    const unsigned short* rp = &row_off_s[(t < N_COMBOS ? t : 0) * ROWSTRIDE];

    for (int it = 0; it < N_ITERS; ++it) {
        xb_lds[t] = xb;
        __syncthreads();                                   // A: xb ready
        if (t < N_COMBOS) {
            float s = 0.0f;
            for (int k = 0; k < my_rc; k += 4) {
                unsigned long long w = *(const unsigned long long*)(rp + k);
                s += *(const float*)((const char*)xb_lds + (w & 0xffffULL));
                s += *(const float*)((const char*)xb_lds + ((w >> 16) & 0xffffULL));
                s += *(const float*)((const char*)xb_lds + ((w >> 32) & 0xffffULL));
                s += *(const float*)((const char*)xb_lds + (w >> 48));
            }
            const float u1 = lam1 + sig * s;               // lam1 + sig*(xb S^T)
            lam1 = fmaxf(u1 - sig * b_reg, 0.0f);
            lam1_lds[t] = lam1;
        }
        lam2 = fminf(lam2 + sig * xb, 0.0f);
        __syncthreads();                                   // B: lam1 ready
        float s2 = 0.0f;
        for (int k = 0; k < my_cc; k += 4) {
            unsigned int w = *(const unsigned int*)(cp + k);
            s2 += lam1_lds[w & 255];
            s2 += lam1_lds[(w >> 8) & 255];
            s2 += lam1_lds[(w >> 16) & 255];
            s2 += lam1_lds[w >> 24];
        }
        const float v = x - tau * (s2 + lam2);             // x - tau*(lam1 S + lam2)
        const float u = v + tau - z;                       // + tau*w - z, w = 1
        float p = wave_sum_bcast(u * u);
        if ((t & 63) == 0) red[t >> 6] = p;
        __syncthreads();                                   // C: norm partials ready
        const float4 r0 = *(const float4*)red;
        const float4 r1 = *(const float4*)(red + 4);
        const float nrm = sqrtf(r0.x + r0.y + r0.z + r0.w + r1.x + r1.y + r1.z + r1.w);
        const float scale = fmaxf(0.0f, 1.0f - tau * 10.0f / fmaxf(nrm, 1e-12f));
        const float xn = z + scale * u;
        xb = 2.0f * xn - x;
        x  = xn;
    }

    out[row * N_STRUCTS + t] = x;
}

extern "C" void kernel_launch(void* const* d_in, const int* in_sizes, int n_in,
                              void* d_out, int out_size, void* d_ws, size_t ws_size,
                              hipStream_t stream)
{
    const float* X  = (const float*)d_in[0];
    const float* W1 = (const float*)d_in[1];
    const float* b1 = (const float*)d_in[2];
    const float* W2 = (const float*)d_in[3];
    const float* b2 = (const float*)d_in[4];
    const float* W3 = (const float*)d_in[5];
    const float* b3 = (const float*)d_in[6];
    const float* W4 = (const float*)d_in[7];
    const float* b4 = (const float*)d_in[8];
    const float* S  = (const float*)d_in[9];
    float* out = (float*)d_out;

    char* ws = (char*)d_ws;
    float*          tau_ws    = (float*)(ws + 0);
    int*            col_cnt_g = (int*)(ws + 64);
    unsigned char*  col_idx_g = (unsigned char*)(ws + 2112);
    int*            row_cnt_g = (int*)(ws + 16448);
    unsigned short* row_off_g = (unsigned short*)(ws + 16960);

    prep_kernel<<<1, 512, 0, stream>>>(S, tau_ws, col_cnt_g, col_idx_g,
                                       row_cnt_g, row_off_g);
    solve_kernel<<<BATCH, 512, 0, stream>>>(X, W1, b1, W2, b2, W3, b3, W4, b4,
                                            tau_ws, col_cnt_g, col_idx_g,
                                            row_cnt_g, row_off_g, out);
}

// Round 3
// 341.582 us; speedup vs baseline: 1.7604x; 1.2172x over previous
//
#include <hip/hip_runtime.h>
#include <hip/hip_bf16.h>

// MatchNet: MLP -> batched PDHG LP solve.
// B=2048 rows; m=128 (combos), n=512 (structures); 60 PDHG iters; CONTROL=10.
// R=2 batch rows per 512-thread block (1024 blocks): all gathers are
// ds_read_b64 of [idx][2] pairs so index words, barriers and address math are
// amortized over 2 rows. Col index lists live in REGISTERS (static unroll).
// Prep: chunked-prefetch scan + bitmask row-list build (sorted by construction,
// no insertion sort), then the 30-step power iteration for L.

#define N_COMBOS   128
#define N_STRUCTS  512
#define BATCH      2048
#define HID        20
#define N_ITERS    60
#define COLCAP     24   // exported u16 entries per col (mean nnz ~4, max ~14)
#define ROWCAP     48   // max real nnz per row (mean ~16, max ~30)
#define COLSTRIDE  28   // prep-internal u8 entries per col
#define ROWSTRIDE  52   // u16 entries per row list

// ---------------- workspace layout (bytes) ----------------
// 0     : float tau (= sig = 0.9/L)
// 64    : int col_cnt4[512]               (2048 B)  padded counts (mult of 4, <=24)
// 2112  : u16 col_off[512*24]             (24576 B) byte offsets idx*8 (dummies -> lam1 pad)
// 26688 : int row_cnt4[128]               (512 B)
// 27200 : u16 row_off[128*52]             (13312 B) byte offsets idx*8 (dummies -> xb pad)
// total 40512 B

__device__ __forceinline__ float wave_sum_bcast(float x) {
    float s = x;
    s += __builtin_bit_cast(float, __builtin_amdgcn_update_dpp(0, __builtin_bit_cast(int, s), 0x111, 0xf, 0xf, true)); // row_shr:1
    s += __builtin_bit_cast(float, __builtin_amdgcn_update_dpp(0, __builtin_bit_cast(int, s), 0x112, 0xf, 0xf, true)); // row_shr:2
    s += __builtin_bit_cast(float, __builtin_amdgcn_update_dpp(0, __builtin_bit_cast(int, s), 0x114, 0xf, 0xf, true)); // row_shr:4
    s += __builtin_bit_cast(float, __builtin_amdgcn_update_dpp(0, __builtin_bit_cast(int, s), 0x118, 0xf, 0xf, true)); // row_shr:8
    s += __builtin_bit_cast(float, __builtin_amdgcn_update_dpp(0, __builtin_bit_cast(int, s), 0x142, 0xa, 0xf, true)); // row_bcast:15
    s += __builtin_bit_cast(float, __builtin_amdgcn_update_dpp(0, __builtin_bit_cast(int, s), 0x143, 0xc, 0xf, true)); // row_bcast:31
    return __builtin_bit_cast(float, __builtin_amdgcn_readlane(__builtin_bit_cast(int, s), 63));
}

__global__ __launch_bounds__(512) void prep_kernel(
    const float* __restrict__ S,
    float* __restrict__ tau_ws,
    int* __restrict__ col_cnt_g, unsigned short* __restrict__ col_off_g,
    int* __restrict__ row_cnt_g, unsigned short* __restrict__ row_off_g)
{
    __shared__ unsigned int rowbits[N_COMBOS][16];
    __shared__ alignas(16) unsigned short row_lst[N_COMBOS * ROWSTRIDE]; // byte offs *4 (into v_lds)
    __shared__ alignas(8)  unsigned char  col_idx_s[N_STRUCTS * COLSTRIDE]; // raw idx, 128..131 dummy
    __shared__ alignas(16) float v_lds[N_STRUCTS + 4];
    __shared__ alignas(16) float sv_lds[N_COMBOS + 4];
    __shared__ alignas(16) float red[8];

    const int t = threadIdx.x;
    {   // zero row bitmasks (128*16 u32 = 2048)
        unsigned int* rb = &rowbits[0][0];
        rb[t] = 0u; rb[t + 512] = 0u; rb[t + 1024] = 0u; rb[t + 1536] = 0u;
    }
    if (t < 4) { v_lds[N_STRUCTS + t] = 0.0f; sv_lds[N_COMBOS + t] = 0.0f; }
    __syncthreads();

    // ---- scan column t: chunked register prefetch (pipelines global loads) ----
    int cc = 0;
    for (int ch = 0; ch < 8; ++ch) {
        float vals[16];
#pragma unroll
        for (int j = 0; j < 16; ++j) vals[j] = S[(ch * 16 + j) * N_STRUCTS + t];
#pragma unroll
        for (int j = 0; j < 16; ++j) {
            if (vals[j] != 0.0f) {
                const int i = ch * 16 + j;
                if (cc < COLCAP) col_idx_s[t * COLSTRIDE + cc] = (unsigned char)i;
                ++cc;
                atomicOr(&rowbits[i][t >> 5], 1u << (t & 31));
            }
        }
    }
    if (cc > COLCAP) cc = COLCAP;
    const int my_cc = (cc + 3) & ~3;
    for (int k = 0; k < COLSTRIDE; ++k)
        if (k >= cc) col_idx_s[t * COLSTRIDE + k] = (unsigned char)(N_COMBOS + (k & 3));
    __syncthreads();

    // ---- build row lists from bitmasks: sorted by construction ----
    int my_rc = 0;
    if (t < N_COMBOS) {
        unsigned short* L = &row_lst[t * ROWSTRIDE];
        int c = 0;
#pragma unroll
        for (int g = 0; g < 16; ++g) {
            unsigned int w = rowbits[t][g];
            while (w) {
                const int b = __ffs(w) - 1;
                if (c < ROWCAP) L[c] = (unsigned short)((g * 32 + b) * 4);
                ++c;
                w &= w - 1;
            }
        }
        if (c > ROWCAP) c = ROWCAP;
        my_rc = (c + 3) & ~3;
        for (int k = c; k < ROWSTRIDE; ++k)
            L[k] = (unsigned short)((N_STRUCTS + (k & 3)) * 4);
        row_cnt_g[t] = my_rc;
    }
    v_lds[t] = 1.0f;
    __syncthreads();

    // ---- power iteration: 30 normalize steps, then quadratic form ----
    const unsigned short* rp = &row_lst[(t < N_COMBOS ? t : 0) * ROWSTRIDE];
    const unsigned char*  cp = &col_idx_s[t * COLSTRIDE];
    for (int it = 0; it <= 30; ++it) {
        if (t < N_COMBOS) {
            float s = 0.0f;
            for (int k = 0; k < my_rc; k += 4) {
                unsigned long long w = *(const unsigned long long*)(rp + k);
                s += *(const float*)((const char*)v_lds + (w & 0xffffULL));
                s += *(const float*)((const char*)v_lds + ((w >> 16) & 0xffffULL));
                s += *(const float*)((const char*)v_lds + ((w >> 32) & 0xffffULL));
                s += *(const float*)((const char*)v_lds + (w >> 48));
            }
            sv_lds[t] = s;
        }
        __syncthreads();
        float u;
        {
            float s = 0.0f;
            for (int k = 0; k < my_cc; k += 4) {
                unsigned int w = *(const unsigned int*)(cp + k);
                s += sv_lds[w & 255];
                s += sv_lds[(w >> 8) & 255];
                s += sv_lds[(w >> 16) & 255];
                s += sv_lds[w >> 24];
            }
            u = s + v_lds[t];                    // (S^T S + I) v
        }
        float p = (it < 30) ? u * u : u * v_lds[t];
        p = wave_sum_bcast(p);
        if ((t & 63) == 0) red[t >> 6] = p;
        __syncthreads();
        const float4 r0 = *(const float4*)red;
        const float4 r1 = *(const float4*)(red + 4);
        const float tot = r0.x + r0.y + r0.z + r0.w + r1.x + r1.y + r1.z + r1.w;
        if (it < 30) {
            const float nrm = sqrtf(tot);
            v_lds[t] = u / nrm;
            __syncthreads();
        } else {
            if (t == 0) tau_ws[0] = 0.9f / sqrtf(tot);
        }
    }

    // ---- export: col lists as u16 byte-offsets (*8) packed for the solver ----
    col_cnt_g[t] = my_cc;
    {
        const unsigned char* c8 = &col_idx_s[t * COLSTRIDE];
#define PK(k) ((((unsigned int)c8[k]) << 3) | (((unsigned int)c8[(k) + 1]) << 19))
        uint4 o0 = { PK(0), PK(2),  PK(4),  PK(6)  };
        uint4 o1 = { PK(8), PK(10), PK(12), PK(14) };
        uint4 o2 = { PK(16),PK(18), PK(20), PK(22) };
#undef PK
        uint4* dst = (uint4*)col_off_g;
        dst[t * 3 + 0] = o0; dst[t * 3 + 1] = o1; dst[t * 3 + 2] = o2;
    }
    if (t < N_COMBOS) {   // row offsets: *4 -> *8 (solver layout is [idx][2] f32)
        const unsigned short* L = &row_lst[t * ROWSTRIDE];
        unsigned int* dst = (unsigned int*)row_off_g;
        for (int k = 0; k < ROWSTRIDE; k += 2) {
            unsigned int w = ((unsigned int)(L[k] << 1)) |
                             (((unsigned int)(L[k + 1] << 1)) << 16);
            dst[t * (ROWSTRIDE / 2) + (k >> 1)] = w;
        }
    }
}

__global__ __launch_bounds__(512) void solve_kernel(
    const float* __restrict__ X,
    const float* __restrict__ W1, const float* __restrict__ b1,
    const float* __restrict__ W2, const float* __restrict__ b2,
    const float* __restrict__ W3, const float* __restrict__ b3,
    const float* __restrict__ W4, const float* __restrict__ b4,
    const float* __restrict__ tau_ws,
    const int* __restrict__ col_cnt_g, const unsigned short* __restrict__ col_off_g,
    const int* __restrict__ row_cnt_g, const unsigned short* __restrict__ row_off_g,
    float* __restrict__ out)
{
    __shared__ alignas(16) float xb_lds[2 * N_STRUCTS + 8];   // [512][2] + zero pad
    __shared__ alignas(16) float lam1_lds[2 * N_COMBOS + 8];  // [128][2] + zero pad
    __shared__ alignas(16) float b_lds[2 * N_COMBOS];         // [128][2]
    __shared__ alignas(16) float red[16];                     // [8 waves][2 rows]
    __shared__ float ha[2][HID], hb[2][HID];
    __shared__ alignas(16) unsigned short row_off_s[N_COMBOS * ROWSTRIDE];

    const int t  = threadIdx.x;
    const int r0 = blockIdx.x * 2, r1 = r0 + 1;

    // ---- stage row lists (13312 B = 832 uint4) ----
    {
        const uint4* g = (const uint4*)row_off_g;  uint4* l = (uint4*)row_off_s;
        l[t] = g[t];
        if (t < 320) l[512 + t] = g[512 + t];
    }
    // ---- col offsets -> registers (static unroll below) ----
    uint4 ca, cb, cw;
    {
        const uint4* g = (const uint4*)col_off_g;
        ca = g[t * 3]; cb = g[t * 3 + 1]; cw = g[t * 3 + 2];
    }
    const int my_cc = col_cnt_g[t];
    int my_rc = 0;
    float b0 = 0.0f, bv1 = 0.0f;
    if (t < N_COMBOS) {
        my_rc = row_cnt_g[t];
        b0  = X[r0 * N_COMBOS + t];
        bv1 = X[r1 * N_COMBOS + t];
        ((float2*)b_lds)[t] = make_float2(b0, bv1);
    }
    if (t < 8) { xb_lds[2 * N_STRUCTS + t] = 0.0f; lam1_lds[2 * N_COMBOS + t] = 0.0f; }
    __syncthreads();

    // ---- MLP (two rows via threads 0..39) ----
    if (t < 2 * HID) {
        const int r = t >= HID, tt = t - r * HID;
        float s = b1[tt];
        for (int k = 0; k < N_COMBOS; ++k) s = fmaf(b_lds[k * 2 + r], W1[k * HID + tt], s);
        ha[r][tt] = tanhf(s);
    }
    __syncthreads();
    if (t < 2 * HID) {
        const int r = t >= HID, tt = t - r * HID;
        float s = b2[tt];
        for (int k = 0; k < HID; ++k) s = fmaf(ha[r][k], W2[k * HID + tt], s);
        hb[r][tt] = tanhf(s);
    }
    __syncthreads();
    if (t < 2 * HID) {
        const int r = t >= HID, tt = t - r * HID;
        float s = b3[tt];
        for (int k = 0; k < HID; ++k) s = fmaf(hb[r][k], W3[k * HID + tt], s);
        ha[r][tt] = tanhf(s);
    }
    __syncthreads();
    float z0 = b4[t], z1 = z0;
    for (int h = 0; h < HID; ++h) {
        const float w = W4[h * N_STRUCTS + t];
        z0 = fmaf(ha[0][h], w, z0);
        z1 = fmaf(ha[1][h], w, z1);
    }

    const float tau = tau_ws[0];
    const float sig = tau;

    // ---- PDHG ----
    float x0 = fmaxf(z0, 0.0f), x1 = fmaxf(z1, 0.0f);
    float xb0 = x0, xb1 = x1;
    float l10 = 0.0f, l11 = 0.0f;      // duals for S x <= b (threads < 128)
    float l20 = 0.0f, l21 = 0.0f;      // duals for x >= 0

    const unsigned short* rp = &row_off_s[(t < N_COMBOS ? t : 0) * ROWSTRIDE];
    const char* xbB = (const char*)xb_lds;
    const char* lmB = (const char*)lam1_lds;

    for (int it = 0; it < N_ITERS; ++it) {
        ((float2*)xb_lds)[t] = make_float2(xb0, xb1);
        __syncthreads();                                   // A: xb ready
        if (t < N_COMBOS) {
            float s0 = 0.0f, s1 = 0.0f;
            for (int k = 0; k < my_rc; k += 4) {
                const unsigned long long w = *(const unsigned long long*)(rp + k);
                const float2 a = *(const float2*)(xbB + (w & 0xffffULL));
                const float2 b = *(const float2*)(xbB + ((w >> 16) & 0xffffULL));
                const float2 c = *(const float2*)(xbB + ((w >> 32) & 0xffffULL));
                const float2 d = *(const float2*)(xbB + (w >> 48));
                s0 += a.x; s1 += a.y; s0 += b.x; s1 += b.y;
                s0 += c.x; s1 += c.y; s0 += d.x; s1 += d.y;
            }
            l10 = fmaxf(l10 + sig * s0 - sig * b0,  0.0f);
            l11 = fmaxf(l11 + sig * s1 - sig * bv1, 0.0f);
            ((float2*)lam1_lds)[t] = make_float2(l10, l11);
        }
        l20 = fminf(l20 + sig * xb0, 0.0f);
        l21 = fminf(l21 + sig * xb1, 0.0f);
        __syncthreads();                                   // B: lam1 ready
        float s20 = 0.0f, s21 = 0.0f;
#define CGW(W) { const float2 a = *(const float2*)(lmB + ((W) & 0xffffu)); \
                 const float2 b = *(const float2*)(lmB + ((W) >> 16));     \
                 s20 += a.x; s21 += a.y; s20 += b.x; s21 += b.y; }
        if (my_cc > 0)  { CGW(ca.x) CGW(ca.y) }
        if (my_cc > 4)  { CGW(ca.z) CGW(ca.w) }
        if (my_cc > 8)  { CGW(cb.x) CGW(cb.y) }
        if (my_cc > 12) { CGW(cb.z) CGW(cb.w) }
        if (my_cc > 16) { CGW(cw.x) CGW(cw.y) }
        if (my_cc > 20) { CGW(cw.z) CGW(cw.w) }
#undef CGW
        const float v0 = x0 - tau * (s20 + l20);
        const float v1 = x1 - tau * (s21 + l21);
        const float u0 = v0 + tau - z0;
        const float u1 = v1 + tau - z1;
        const float p0 = wave_sum_bcast(u0 * u0);
        const float p1 = wave_sum_bcast(u1 * u1);
        if ((t & 63) == 0) ((float2*)red)[t >> 6] = make_float2(p0, p1);
        __syncthreads();                                   // C: norm partials ready
        const float4 A = ((const float4*)red)[0];
        const float4 B = ((const float4*)red)[1];
        const float4 C = ((const float4*)red)[2];
        const float4 D = ((const float4*)red)[3];
        const float tot0 = A.x + A.z + B.x + B.z + C.x + C.z + D.x + D.z;
        const float tot1 = A.y + A.w + B.y + B.w + C.y + C.w + D.y + D.w;
        const float sc0 = fmaxf(0.0f, 1.0f - tau * 10.0f / fmaxf(sqrtf(tot0), 1e-12f));
        const float sc1 = fmaxf(0.0f, 1.0f - tau * 10.0f / fmaxf(sqrtf(tot1), 1e-12f));
        const float xn0 = z0 + sc0 * u0;
        const float xn1 = z1 + sc1 * u1;
        xb0 = 2.0f * xn0 - x0;  xb1 = 2.0f * xn1 - x1;
        x0 = xn0;  x1 = xn1;
    }

    out[r0 * N_STRUCTS + t] = x0;
    out[r1 * N_STRUCTS + t] = x1;
}

extern "C" void kernel_launch(void* const* d_in, const int* in_sizes, int n_in,
                              void* d_out, int out_size, void* d_ws, size_t ws_size,
                              hipStream_t stream)
{
    const float* X  = (const float*)d_in[0];
    const float* W1 = (const float*)d_in[1];
    const float* b1 = (const float*)d_in[2];
    const float* W2 = (const float*)d_in[3];
    const float* b2 = (const float*)d_in[4];
    const float* W3 = (const float*)d_in[5];
    const float* b3 = (const float*)d_in[6];
    const float* W4 = (const float*)d_in[7];
    const float* b4 = (const float*)d_in[8];
    const float* S  = (const float*)d_in[9];
    float* out = (float*)d_out;

    char* ws = (char*)d_ws;
    float*          tau_ws    = (float*)(ws + 0);
    int*            col_cnt_g = (int*)(ws + 64);
    unsigned short* col_off_g = (unsigned short*)(ws + 2112);
    int*            row_cnt_g = (int*)(ws + 26688);
    unsigned short* row_off_g = (unsigned short*)(ws + 27200);

    prep_kernel<<<1, 512, 0, stream>>>(S, tau_ws, col_cnt_g, col_off_g,
                                       row_cnt_g, row_off_g);
    solve_kernel<<<BATCH / 2, 512, 0, stream>>>(X, W1, b1, W2, b2, W3, b3, W4, b4,
                                                tau_ws, col_cnt_g, col_off_g,
                                                row_cnt_g, row_off_g, out);
}

// Round 5
// 280.859 us; speedup vs baseline: 2.1410x; 1.2162x over previous
//
#include <hip/hip_runtime.h>

// MatchNet: MLP -> batched PDHG LP solve. B=2048 rows; m=128; n=512; 60 iters.
// Solve: 1024 blocks x 512 thr, 2 batch rows/block. 2 barriers/iter:
//   - xb never published: publish {A=2z-x, B=2u}; gather Sxb = SA + sc*SB.
//   - row gather quad-split: row r <-> lanes 4r..4r+3, DPP quad-perm combine.
//   - all index lists in registers; norm via LDS f32 atomics + rsqrt.
// Prep: 4-block coalesced scan (col masks + transposed row bitmasks), then
// 1-block finish: list build (sorted by construction) + 31-iter power iter.

#define NC    128
#define NS    512
#define BATCH 2048
#define HID   20

typedef unsigned int  uint;
typedef unsigned short ushort;

// ---------------- workspace layout (bytes) ----------------
// 0     : float tau
// 64    : u32 colmask[512*4]   (8192)   bit i of word g = S[32g+i][col]
// 8256  : u32 rowbits[128*16]  (8192)   bit c of word w = S[row][32w+c]
// 16448 : u32 col_meta[512*8]  (16384)  16 u16 byte-addrs (*8) into lam1_lds
// 32832 : u32 col_cnt[512]     (2048)   even, <=16 (dummy -> lam1_lds[128]=0)
// 34880 : u32 row_meta[512*8]  (16384)  per (row,quad): 10 u16 byte-addrs (*16)
// 51264 : u32 row_cnt[512]     (2048)   even, <=10 (dummy -> ab_lds[512]=0)

template <int CTRL, int RMASK = 0xf>
__device__ __forceinline__ float dppadd(float s) {
    return s + __builtin_bit_cast(float,
        __builtin_amdgcn_update_dpp(0, __builtin_bit_cast(int, s), CTRL, RMASK, 0xf, true));
}
__device__ __forceinline__ float quad_sum(float s) {   // total in all 4 lanes of quad
    s = dppadd<0xB1>(s);   // quad_perm [1,0,3,2]
    s = dppadd<0x4E>(s);   // quad_perm [2,3,0,1]
    return s;
}
__device__ __forceinline__ float wave_sum_bcast(float x) {
    float s = x;
    s = dppadd<0x111>(s);  // row_shr:1
    s = dppadd<0x112>(s);  // row_shr:2
    s = dppadd<0x114>(s);  // row_shr:4
    s = dppadd<0x118>(s);  // row_shr:8
    s = dppadd<0x142, 0xa>(s);  // row_bcast:15
    s = dppadd<0x143, 0xc>(s);  // row_bcast:31
    return __builtin_bit_cast(float, __builtin_amdgcn_readlane(__builtin_bit_cast(int, s), 63));
}

// ---- prep 1: block g scans rows [32g,32g+32) x all 512 cols (coalesced) ----
__global__ __launch_bounds__(512) void prep_scan(
    const float* __restrict__ S, uint* __restrict__ colmask_g, uint* __restrict__ rowbits_g)
{
    __shared__ uint mcol[NS];
    const int t = threadIdx.x, g = blockIdx.x;
    float vals[32];
#pragma unroll
    for (int j = 0; j < 32; ++j) vals[j] = S[(g * 32 + j) * NS + t];
    uint m = 0;
#pragma unroll
    for (int j = 0; j < 32; ++j) if (vals[j] != 0.0f) m |= (1u << j);
    mcol[t] = m;
    colmask_g[t * 4 + g] = m;
    __syncthreads();
    const int j = t >> 4, w = t & 15;                  // 32 rows x 16 words
    uint val = 0;
#pragma unroll
    for (int c = 0; c < 32; ++c)
        val |= (((mcol[w * 32 + c] >> j) & 1u) << c);
    rowbits_g[(g * 32 + j) * 16 + w] = val;
}

// ---- prep 2: build lists + power iteration for tau ----
__global__ __launch_bounds__(512) void prep_finish(
    const uint* __restrict__ colmask_g, const uint* __restrict__ rowbits_g,
    float* __restrict__ tau_ws,
    uint* __restrict__ col_meta, uint* __restrict__ col_cnt_g,
    uint* __restrict__ row_meta, uint* __restrict__ row_cnt_g)
{
    __shared__ ushort clist[NS][16];
    __shared__ ushort rql[NS][10];
    __shared__ int    ccnt_l[NS];
    __shared__ int    rcnt_l[NS];
    __shared__ float  u_lds[NS + 1];
    __shared__ float  sv_lds[NC];
    __shared__ float  red_pi[32];
    const int t = threadIdx.x;

    uint cm[4];
    { const uint4 c4 = *(const uint4*)&colmask_g[t * 4];
      cm[0] = c4.x; cm[1] = c4.y; cm[2] = c4.z; cm[3] = c4.w; }
    // col list (ascending rows), byte-addrs *8 into lam1_lds; pad -> 128*8
    {
        int cc = 0;
#pragma unroll
        for (int g = 0; g < 4; ++g) {
            uint m = cm[g];
            while (m) {
                const int b = __ffs(m) - 1; m &= m - 1;
                if (cc < 16) clist[t][cc] = (ushort)((g * 32 + b) * 8);
                ++cc;
            }
        }
        if (cc > 16) cc = 16;
        const int cc2 = (cc + 1) & ~1;
        for (int k = cc; k < 16; ++k) clist[t][k] = (ushort)(NC * 8);
        ccnt_l[t] = cc2;
    }
    // row quarter lists (entry e -> quarter e&3), byte-addrs *16 into ab_lds
    if (t < NC) {
#pragma unroll
        for (int q = 0; q < 4; ++q)
            for (int p = 0; p < 10; ++p) rql[t * 4 + q][p] = (ushort)(NS * 16);
        uint rb[16];
        { const uint4 a = *(const uint4*)&rowbits_g[t * 16];
          const uint4 b = *(const uint4*)&rowbits_g[t * 16 + 4];
          const uint4 c = *(const uint4*)&rowbits_g[t * 16 + 8];
          const uint4 d = *(const uint4*)&rowbits_g[t * 16 + 12];
          rb[0]=a.x; rb[1]=a.y; rb[2]=a.z;  rb[3]=a.w;  rb[4]=b.x;  rb[5]=b.y;  rb[6]=b.z;  rb[7]=b.w;
          rb[8]=c.x; rb[9]=c.y; rb[10]=c.z; rb[11]=c.w; rb[12]=d.x; rb[13]=d.y; rb[14]=d.z; rb[15]=d.w; }
        int e = 0;
#pragma unroll
        for (int w = 0; w < 16; ++w) {
            uint m = rb[w];
            while (m) {
                const int b = __ffs(m) - 1; m &= m - 1;
                const int q = e & 3, p = e >> 2;
                if (p < 10) rql[t * 4 + q][p] = (ushort)((w * 32 + b) * 16);
                ++e;
            }
        }
#pragma unroll
        for (int q = 0; q < 4; ++q) {
            int n = (e - q + 3) >> 2;
            if (n < 0) n = 0;
            if (n > 10) n = 10;
            rcnt_l[t * 4 + q] = (n + 1) & ~1;
        }
    }
    if (t == 0) u_lds[NS] = 0.0f;
    if (t < 32) red_pi[t] = 0.0f;
    u_lds[t] = 1.0f;
    __syncthreads();

    // export
    {
        uint4* cm4 = (uint4*)col_meta;
        cm4[t * 2 + 0] = *(const uint4*)&clist[t][0];
        cm4[t * 2 + 1] = *(const uint4*)&clist[t][8];
        col_cnt_g[t] = (uint)ccnt_l[t];
        const ushort* rp = rql[t];
#pragma unroll
        for (int k = 0; k < 5; ++k)
            row_meta[t * 8 + k] = (uint)rp[2 * k] | ((uint)rp[2 * k + 1] << 16);
        row_cnt_g[t] = (uint)rcnt_l[t];
    }

    // power iteration: 31 iters, quad-split rows, 2 barriers/iter
    const int rcn = rcnt_l[t];
    float u_loc = 1.0f;
    for (int it = 0; it <= 30; ++it) {
        const float inv = it ? rsqrtf(red_pi[it - 1]) : 1.0f;
        float s = 0.0f;
        for (int k = 0; k < rcn; ++k) {
            const uint a = rql[t][k];
            s += *(const float*)((const char*)u_lds + (a >> 2));   // *16 -> *4
        }
        s = quad_sum(s * inv);
        if ((t & 3) == 3) sv_lds[t >> 2] = s;
        __syncthreads();
        const float vt = u_loc * inv;
        float w = vt;
#pragma unroll
        for (int g = 0; g < 4; ++g) {
            uint m = cm[g];
            while (m) { const int b = __ffs(m) - 1; m &= m - 1; w += sv_lds[g * 32 + b]; }
        }
        float p = (it < 30) ? w * w : w * vt;
        p = wave_sum_bcast(p);
        if ((t & 63) == 0) atomicAdd(&red_pi[it], p);
        u_lds[t] = w;
        u_loc = w;
        __syncthreads();
    }
    if (t == 0) tau_ws[0] = 0.9f / sqrtf(red_pi[30]);
}

// ---- main solve ----
__global__ __launch_bounds__(512, 8) void solve_kernel(
    const float* __restrict__ X,
    const float* __restrict__ W1, const float* __restrict__ b1,
    const float* __restrict__ W2, const float* __restrict__ b2,
    const float* __restrict__ W3, const float* __restrict__ b3,
    const float* __restrict__ W4, const float* __restrict__ b4,
    const float* __restrict__ tau_ws,
    const uint* __restrict__ col_meta, const uint* __restrict__ col_cnt_g,
    const uint* __restrict__ row_meta, const uint* __restrict__ row_cnt_g,
    float* __restrict__ out)
{
    __shared__ alignas(16) float4 ab_lds[NS + 1];     // {A0,B0,A1,B1} per struct
    __shared__ alignas(16) float2 lam1_lds[NC + 1];
    __shared__ alignas(16) float  red[61][2];         // slot 60 = zeros (iter -1)
    __shared__ alignas(16) float2 b_lds[NC];
    __shared__ float ha[2][HID], hb[2][HID];

    const int t  = threadIdx.x;
    const int r0 = blockIdx.x * 2, r1 = r0 + 1;

    uint ca[8];
    { const uint4 a = *(const uint4*)&col_meta[t * 8];
      const uint4 b = *(const uint4*)&col_meta[t * 8 + 4];
      ca[0]=a.x; ca[1]=a.y; ca[2]=a.z; ca[3]=a.w; ca[4]=b.x; ca[5]=b.y; ca[6]=b.z; ca[7]=b.w; }
    const int cc = (int)col_cnt_g[t];
    uint ra[5];
    { const uint4 a = *(const uint4*)&row_meta[t * 8];
      ra[0]=a.x; ra[1]=a.y; ra[2]=a.z; ra[3]=a.w; ra[4]=row_meta[t * 8 + 4]; }
    const int rcn = (int)row_cnt_g[t];

    if (t == 0) { ab_lds[NS] = make_float4(0,0,0,0); lam1_lds[NC] = make_float2(0,0); }
    if (t < 122) ((float*)red)[t] = 0.0f;
    if (t < NC) b_lds[t] = make_float2(X[r0 * NC + t], X[r1 * NC + t]);
    __syncthreads();

    // MLP (two rows on threads 0..39)
    if (t < 2 * HID) {
        const int rr = t >= HID, tt = t - rr * HID;
        float s = b1[tt];
        for (int k = 0; k < NC; ++k)
            s = fmaf(rr ? b_lds[k].y : b_lds[k].x, W1[k * HID + tt], s);
        ha[rr][tt] = tanhf(s);
    }
    __syncthreads();
    if (t < 2 * HID) {
        const int rr = t >= HID, tt = t - rr * HID;
        float s = b2[tt];
        for (int k = 0; k < HID; ++k) s = fmaf(ha[rr][k], W2[k * HID + tt], s);
        hb[rr][tt] = tanhf(s);
    }
    __syncthreads();
    if (t < 2 * HID) {
        const int rr = t >= HID, tt = t - rr * HID;
        float s = b3[tt];
        for (int k = 0; k < HID; ++k) s = fmaf(hb[rr][k], W3[k * HID + tt], s);
        ha[rr][tt] = tanhf(s);
    }
    __syncthreads();
    float z0 = b4[t], z1 = z0;
    for (int h = 0; h < HID; ++h) {
        const float w = W4[h * NS + t];
        z0 = fmaf(ha[0][h], w, z0);
        z1 = fmaf(ha[1][h], w, z1);
    }

    const float tau = tau_ws[0];
    const float sig = tau;
    const float c10 = 10.0f * tau;
    const int r = t >> 2, q = t & 3;
    const float bb0 = b_lds[r].x, bb1 = b_lds[r].y;

    float x0 = fmaxf(z0, 0.f), x1 = fmaxf(z1, 0.f);
    float xb0 = x0, xb1 = x1;
    float u0 = 0.f, u1 = 0.f;
    float A0 = x0, B0 = 0.f, A1 = x1, B1 = 0.f;
    float l10 = 0.f, l11 = 0.f, l20 = 0.f, l21 = 0.f;
    ab_lds[t] = make_float4(A0, B0, A1, B1);
    __syncthreads();

    int prev = 60;
    for (int it = 0; it < 60; ++it) {
        // --- top: finish prev iter's primal update (local) ---
        const float2 rr2 = *(const float2*)red[prev];
        const float sc0 = fmaxf(0.f, 1.f - c10 * rsqrtf(rr2.x));
        const float sc1 = fmaxf(0.f, 1.f - c10 * rsqrtf(rr2.y));
        if (it) {
            x0 = fmaf(sc0, u0, z0);   x1 = fmaf(sc1, u1, z1);
            xb0 = fmaf(sc0, B0, A0);  xb1 = fmaf(sc1, B1, A1);
        }
        l20 = fminf(fmaf(sig, xb0, l20), 0.f);
        l21 = fminf(fmaf(sig, xb1, l21), 0.f);
        // --- row gather (quad-split, all 512 lanes) ---
        float sA0 = 0.f, sB0 = 0.f, sA1 = 0.f, sB1 = 0.f;
        {
            const char* base = (const char*)ab_lds;
#define RG(K) if ((K) * 2 < rcn) { const uint wv = ra[K];                      \
            const float4 g1 = *(const float4*)(base + (wv & 0xffffu));         \
            const float4 g2 = *(const float4*)(base + (wv >> 16));             \
            sA0 += g1.x + g2.x; sB0 += g1.y + g2.y;                            \
            sA1 += g1.z + g2.z; sB1 += g1.w + g2.w; }
            RG(0) RG(1) RG(2) RG(3) RG(4)
#undef RG
        }
        const float s0 = quad_sum(fmaf(sc0, sB0, sA0));
        const float s1 = quad_sum(fmaf(sc1, sB1, sA1));
        l10 = fmaxf(fmaf(sig, s0 - bb0, l10), 0.f);
        l11 = fmaxf(fmaf(sig, s1 - bb1, l11), 0.f);
        if (q == 3) lam1_lds[r] = make_float2(l10, l11);
        __syncthreads();                                  // lam1 ready
        // --- col gather + primal prox prep ---
        float s20 = 0.f, s21 = 0.f;
        {
            const char* lb = (const char*)lam1_lds;
#define CG(K) if ((K) * 2 < cc) { const uint wv = ca[K];                       \
            const float2 g1 = *(const float2*)(lb + (wv & 0xffffu));           \
            const float2 g2 = *(const float2*)(lb + (wv >> 16));               \
            s20 += g1.x + g2.x; s21 += g1.y + g2.y; }
            CG(0) CG(1) CG(2) CG(3) CG(4) CG(5) CG(6) CG(7)
#undef CG
        }
        const float v0 = x0 - tau * (s20 + l20);
        const float v1 = x1 - tau * (s21 + l21);
        u0 = v0 + tau - z0;
        u1 = v1 + tau - z1;
        A0 = 2.f * z0 - x0;  B0 = 2.f * u0;
        A1 = 2.f * z1 - x1;  B1 = 2.f * u1;
        ab_lds[t] = make_float4(A0, B0, A1, B1);
        const float p0 = wave_sum_bcast(u0 * u0);
        const float p1 = wave_sum_bcast(u1 * u1);
        if ((t & 63) == 0) { atomicAdd(&red[it][0], p0); atomicAdd(&red[it][1], p1); }
        prev = it;
        __syncthreads();                                  // A/B + red ready
    }
    const float2 rr2 = *(const float2*)red[59];
    const float sc0 = fmaxf(0.f, 1.f - c10 * rsqrtf(rr2.x));
    const float sc1 = fmaxf(0.f, 1.f - c10 * rsqrtf(rr2.y));
    out[r0 * NS + t] = fmaf(sc0, u0, z0);
    out[r1 * NS + t] = fmaf(sc1, u1, z1);
}

extern "C" void kernel_launch(void* const* d_in, const int* in_sizes, int n_in,
                              void* d_out, int out_size, void* d_ws, size_t ws_size,
                              hipStream_t stream)
{
    const float* X  = (const float*)d_in[0];
    const float* W1 = (const float*)d_in[1];
    const float* b1 = (const float*)d_in[2];
    const float* W2 = (const float*)d_in[3];
    const float* b2 = (const float*)d_in[4];
    const float* W3 = (const float*)d_in[5];
    const float* b3 = (const float*)d_in[6];
    const float* W4 = (const float*)d_in[7];
    const float* b4 = (const float*)d_in[8];
    const float* S  = (const float*)d_in[9];
    float* out = (float*)d_out;

    char* ws = (char*)d_ws;
    float* tau_ws    = (float*)(ws + 0);
    uint*  colmask_g = (uint*)(ws + 64);
    uint*  rowbits_g = (uint*)(ws + 8256);
    uint*  col_meta  = (uint*)(ws + 16448);
    uint*  col_cnt_g = (uint*)(ws + 32832);
    uint*  row_meta  = (uint*)(ws + 34880);
    uint*  row_cnt_g = (uint*)(ws + 51264);

    prep_scan<<<4, 512, 0, stream>>>(S, colmask_g, rowbits_g);
    prep_finish<<<1, 512, 0, stream>>>(colmask_g, rowbits_g, tau_ws,
                                       col_meta, col_cnt_g, row_meta, row_cnt_g);
    solve_kernel<<<BATCH / 2, 512, 0, stream>>>(X, W1, b1, W2, b2, W3, b3, W4, b4,
                                                tau_ws, col_meta, col_cnt_g,
                                                row_meta, row_cnt_g, out);
}

// Round 6
// 277.678 us; speedup vs baseline: 2.1655x; 1.0115x over previous
//
#include <hip/hip_runtime.h>

// MatchNet: MLP -> batched PDHG LP solve. B=2048 rows; m=128; n=512; 60 iters.
// Solve: 1024 blocks x 512 thr, 2 batch rows/block. 2 barriers/iter:
//   - xb never published: publish {A=2z-x, B=2u}; gather Sxb = SA + sc*SB.
//   - row gather quad-split: row r <-> lanes 4r..4r+3, DPP quad-perm combine.
//   - all index lists in registers; norm via LDS f32 atomics + rsqrt.
//   - row-pair arithmetic in packed fp32 (v_pk_fma_f32 et al) via ext vectors.
// Prep: 4-block coalesced scan (col masks + transposed row bitmasks), then
// 1-block finish: list build (sorted by construction) + 31-iter power iter.

#define NC    128
#define NS    512
#define BATCH 2048
#define HID   20

typedef unsigned int  uint;
typedef unsigned short ushort;
typedef float v2f __attribute__((ext_vector_type(2)));

// ---------------- workspace layout (bytes) ----------------
// 0     : float tau
// 64    : u32 colmask[512*4]   (8192)   bit i of word g = S[32g+i][col]
// 8256  : u32 rowbits[128*16]  (8192)   bit c of word w = S[row][32w+c]
// 16448 : u32 col_meta[512*8]  (16384)  16 u16 byte-addrs (*8) into lam1_lds
// 32832 : u32 col_cnt[512]     (2048)   even, <=16 (dummy -> lam1_lds[128]=0)
// 34880 : u32 row_meta[512*8]  (16384)  per (row,quad): 10 u16 byte-addrs (*16)
// 51264 : u32 row_cnt[512]     (2048)   even, <=10 (dummy -> ab_lds[512]=0)

template <int CTRL, int RMASK = 0xf>
__device__ __forceinline__ float dppadd(float s) {
    return s + __builtin_bit_cast(float,
        __builtin_amdgcn_update_dpp(0, __builtin_bit_cast(int, s), CTRL, RMASK, 0xf, true));
}
__device__ __forceinline__ float quad_sum(float s) {   // total in all 4 lanes of quad
    s = dppadd<0xB1>(s);   // quad_perm [1,0,3,2]
    s = dppadd<0x4E>(s);   // quad_perm [2,3,0,1]
    return s;
}
__device__ __forceinline__ float wave_sum_bcast(float x) {
    float s = x;
    s = dppadd<0x111>(s);  // row_shr:1
    s = dppadd<0x112>(s);  // row_shr:2
    s = dppadd<0x114>(s);  // row_shr:4
    s = dppadd<0x118>(s);  // row_shr:8
    s = dppadd<0x142, 0xa>(s);  // row_bcast:15
    s = dppadd<0x143, 0xc>(s);  // row_bcast:31
    return __builtin_bit_cast(float, __builtin_amdgcn_readlane(__builtin_bit_cast(int, s), 63));
}

__device__ __forceinline__ v2f vfma(v2f a, v2f b, v2f c) { return __builtin_elementwise_fma(a, b, c); }
__device__ __forceinline__ v2f vmax0(v2f a) { const v2f z = {0.f, 0.f}; return __builtin_elementwise_max(a, z); }
__device__ __forceinline__ v2f vmin0(v2f a) { const v2f z = {0.f, 0.f}; return __builtin_elementwise_min(a, z); }

// ---- prep 1: block g scans rows [32g,32g+32) x all 512 cols (coalesced) ----
__global__ __launch_bounds__(512) void prep_scan(
    const float* __restrict__ S, uint* __restrict__ colmask_g, uint* __restrict__ rowbits_g)
{
    __shared__ uint mcol[NS];
    const int t = threadIdx.x, g = blockIdx.x;
    float vals[32];
#pragma unroll
    for (int j = 0; j < 32; ++j) vals[j] = S[(g * 32 + j) * NS + t];
    uint m = 0;
#pragma unroll
    for (int j = 0; j < 32; ++j) if (vals[j] != 0.0f) m |= (1u << j);
    mcol[t] = m;
    colmask_g[t * 4 + g] = m;
    __syncthreads();
    const int j = t >> 4, w = t & 15;                  // 32 rows x 16 words
    uint val = 0;
#pragma unroll
    for (int c = 0; c < 32; ++c)
        val |= (((mcol[w * 32 + c] >> j) & 1u) << c);
    rowbits_g[(g * 32 + j) * 16 + w] = val;
}

// ---- prep 2: build lists + power iteration for tau ----
__global__ __launch_bounds__(512) void prep_finish(
    const uint* __restrict__ colmask_g, const uint* __restrict__ rowbits_g,
    float* __restrict__ tau_ws,
    uint* __restrict__ col_meta, uint* __restrict__ col_cnt_g,
    uint* __restrict__ row_meta, uint* __restrict__ row_cnt_g)
{
    __shared__ ushort clist[NS][16];
    __shared__ ushort rql[NS][10];
    __shared__ int    ccnt_l[NS];
    __shared__ int    rcnt_l[NS];
    __shared__ float  u_lds[NS + 1];
    __shared__ float  sv_lds[NC];
    __shared__ float  red_pi[32];
    const int t = threadIdx.x;

    uint cm[4];
    { const uint4 c4 = *(const uint4*)&colmask_g[t * 4];
      cm[0] = c4.x; cm[1] = c4.y; cm[2] = c4.z; cm[3] = c4.w; }
    // col list (ascending rows), byte-addrs *8 into lam1_lds; pad -> 128*8
    {
        int cc = 0;
#pragma unroll
        for (int g = 0; g < 4; ++g) {
            uint m = cm[g];
            while (m) {
                const int b = __ffs(m) - 1; m &= m - 1;
                if (cc < 16) clist[t][cc] = (ushort)((g * 32 + b) * 8);
                ++cc;
            }
        }
        if (cc > 16) cc = 16;
        const int cc2 = (cc + 1) & ~1;
        for (int k = cc; k < 16; ++k) clist[t][k] = (ushort)(NC * 8);
        ccnt_l[t] = cc2;
    }
    // row quarter lists (entry e -> quarter e&3), byte-addrs *16 into ab_lds
    if (t < NC) {
#pragma unroll
        for (int q = 0; q < 4; ++q)
            for (int p = 0; p < 10; ++p) rql[t * 4 + q][p] = (ushort)(NS * 16);
        uint rb[16];
        { const uint4 a = *(const uint4*)&rowbits_g[t * 16];
          const uint4 b = *(const uint4*)&rowbits_g[t * 16 + 4];
          const uint4 c = *(const uint4*)&rowbits_g[t * 16 + 8];
          const uint4 d = *(const uint4*)&rowbits_g[t * 16 + 12];
          rb[0]=a.x; rb[1]=a.y; rb[2]=a.z;  rb[3]=a.w;  rb[4]=b.x;  rb[5]=b.y;  rb[6]=b.z;  rb[7]=b.w;
          rb[8]=c.x; rb[9]=c.y; rb[10]=c.z; rb[11]=c.w; rb[12]=d.x; rb[13]=d.y; rb[14]=d.z; rb[15]=d.w; }
        int e = 0;
#pragma unroll
        for (int w = 0; w < 16; ++w) {
            uint m = rb[w];
            while (m) {
                const int b = __ffs(m) - 1; m &= m - 1;
                const int q = e & 3, p = e >> 2;
                if (p < 10) rql[t * 4 + q][p] = (ushort)((w * 32 + b) * 16);
                ++e;
            }
        }
#pragma unroll
        for (int q = 0; q < 4; ++q) {
            int n = (e - q + 3) >> 2;
            if (n < 0) n = 0;
            if (n > 10) n = 10;
            rcnt_l[t * 4 + q] = (n + 1) & ~1;
        }
    }
    if (t == 0) u_lds[NS] = 0.0f;
    if (t < 32) red_pi[t] = 0.0f;
    u_lds[t] = 1.0f;
    __syncthreads();

    // export
    {
        uint4* cm4 = (uint4*)col_meta;
        cm4[t * 2 + 0] = *(const uint4*)&clist[t][0];
        cm4[t * 2 + 1] = *(const uint4*)&clist[t][8];
        col_cnt_g[t] = (uint)ccnt_l[t];
        const ushort* rp = rql[t];
#pragma unroll
        for (int k = 0; k < 5; ++k)
            row_meta[t * 8 + k] = (uint)rp[2 * k] | ((uint)rp[2 * k + 1] << 16);
        row_cnt_g[t] = (uint)rcnt_l[t];
    }

    // power iteration: 31 iters, quad-split rows, 2 barriers/iter
    const int rcn = rcnt_l[t];
    float u_loc = 1.0f;
    for (int it = 0; it <= 30; ++it) {
        const float inv = it ? rsqrtf(red_pi[it - 1]) : 1.0f;
        float s = 0.0f;
        for (int k = 0; k < rcn; ++k) {
            const uint a = rql[t][k];
            s += *(const float*)((const char*)u_lds + (a >> 2));   // *16 -> *4
        }
        s = quad_sum(s * inv);
        if ((t & 3) == 3) sv_lds[t >> 2] = s;
        __syncthreads();
        const float vt = u_loc * inv;
        float w = vt;
#pragma unroll
        for (int g = 0; g < 4; ++g) {
            uint m = cm[g];
            while (m) { const int b = __ffs(m) - 1; m &= m - 1; w += sv_lds[g * 32 + b]; }
        }
        float p = (it < 30) ? w * w : w * vt;
        p = wave_sum_bcast(p);
        if ((t & 63) == 0) atomicAdd(&red_pi[it], p);
        u_lds[t] = w;
        u_loc = w;
        __syncthreads();
    }
    if (t == 0) tau_ws[0] = 0.9f / sqrtf(red_pi[30]);
}

// ---- main solve ----
__global__ __launch_bounds__(512, 8) void solve_kernel(
    const float* __restrict__ X,
    const float* __restrict__ W1, const float* __restrict__ b1,
    const float* __restrict__ W2, const float* __restrict__ b2,
    const float* __restrict__ W3, const float* __restrict__ b3,
    const float* __restrict__ W4, const float* __restrict__ b4,
    const float* __restrict__ tau_ws,
    const uint* __restrict__ col_meta, const uint* __restrict__ col_cnt_g,
    const uint* __restrict__ row_meta, const uint* __restrict__ row_cnt_g,
    float* __restrict__ out)
{
    __shared__ alignas(16) float4 ab_lds[NS + 1];     // {A0,B0,A1,B1} per struct
    __shared__ alignas(16) float2 lam1_lds[NC + 1];
    __shared__ alignas(16) float  red[61][2];         // slot 60 = zeros (iter -1)
    __shared__ alignas(16) float2 b_lds[NC];
    __shared__ float ha[2][HID], hb[2][HID];

    const int t  = threadIdx.x;
    const int r0 = blockIdx.x * 2, r1 = r0 + 1;

    uint ca[8];
    { const uint4 a = *(const uint4*)&col_meta[t * 8];
      const uint4 b = *(const uint4*)&col_meta[t * 8 + 4];
      ca[0]=a.x; ca[1]=a.y; ca[2]=a.z; ca[3]=a.w; ca[4]=b.x; ca[5]=b.y; ca[6]=b.z; ca[7]=b.w; }
    const int cc = (int)col_cnt_g[t];
    uint ra[5];
    { const uint4 a = *(const uint4*)&row_meta[t * 8];
      ra[0]=a.x; ra[1]=a.y; ra[2]=a.z; ra[3]=a.w; ra[4]=row_meta[t * 8 + 4]; }
    const int rcn = (int)row_cnt_g[t];

    if (t == 0) { ab_lds[NS] = make_float4(0,0,0,0); lam1_lds[NC] = make_float2(0,0); }
    if (t < 122) ((float*)red)[t] = 0.0f;
    if (t < NC) b_lds[t] = make_float2(X[r0 * NC + t], X[r1 * NC + t]);
    __syncthreads();

    // MLP (two rows on threads 0..39)
    if (t < 2 * HID) {
        const int rr = t >= HID, tt = t - rr * HID;
        float s = b1[tt];
        for (int k = 0; k < NC; ++k)
            s = fmaf(rr ? b_lds[k].y : b_lds[k].x, W1[k * HID + tt], s);
        ha[rr][tt] = tanhf(s);
    }
    __syncthreads();
    if (t < 2 * HID) {
        const int rr = t >= HID, tt = t - rr * HID;
        float s = b2[tt];
        for (int k = 0; k < HID; ++k) s = fmaf(ha[rr][k], W2[k * HID + tt], s);
        hb[rr][tt] = tanhf(s);
    }
    __syncthreads();
    if (t < 2 * HID) {
        const int rr = t >= HID, tt = t - rr * HID;
        float s = b3[tt];
        for (int k = 0; k < HID; ++k) s = fmaf(hb[rr][k], W3[k * HID + tt], s);
        ha[rr][tt] = tanhf(s);
    }
    __syncthreads();
    float z0 = b4[t], z1 = z0;
    for (int h = 0; h < HID; ++h) {
        const float w = W4[h * NS + t];
        z0 = fmaf(ha[0][h], w, z0);
        z1 = fmaf(ha[1][h], w, z1);
    }

    const float tau = tau_ws[0];
    const float c10 = 10.0f * tau;
    const v2f tauv = {tau, tau};
    const v2f sigv = tauv;
    const int r = t >> 2, q = t & 3;
    const v2f bb = {b_lds[r].x, b_lds[r].y};

    const v2f z = {z0, z1};
    v2f x  = vmax0(z);
    v2f xb = x;
    v2f u  = {0.f, 0.f};
    v2f A  = x;                 // published A = 2z - x (init: x)
    v2f Bv = {0.f, 0.f};        // published B = 2u
    v2f l1 = {0.f, 0.f};        // dual for S x <= b  (one per quad-group row)
    v2f l2 = {0.f, 0.f};        // dual for x >= 0
    ab_lds[t] = make_float4(A.x, Bv.x, A.y, Bv.y);
    __syncthreads();

    int prev = 60;
    for (int it = 0; it < 60; ++it) {
        // --- top: finish prev iter's primal update (packed fp32) ---
        const float2 rr2 = *(const float2*)red[prev];
        const v2f sc = {fmaxf(0.f, 1.f - c10 * rsqrtf(rr2.x)),
                        fmaxf(0.f, 1.f - c10 * rsqrtf(rr2.y))};
        if (it) {
            x  = vfma(sc, u, z);
            xb = vfma(sc, Bv, A);
        }
        l2 = vmin0(vfma(sigv, xb, l2));
        // --- row gather (quad-split, all 512 lanes) ---
        v2f gR0 = {0.f, 0.f};   // {sumA, sumB} for batch row 0
        v2f gR1 = {0.f, 0.f};   // {sumA, sumB} for batch row 1
        {
            const char* base = (const char*)ab_lds;
#define RG(K) if ((K) * 2 < rcn) { const uint wv = ra[K];                      \
            const float4 g1 = *(const float4*)(base + (wv & 0xffffu));         \
            const float4 g2 = *(const float4*)(base + (wv >> 16));             \
            gR0 += (v2f){g1.x, g1.y}; gR1 += (v2f){g1.z, g1.w};                \
            gR0 += (v2f){g2.x, g2.y}; gR1 += (v2f){g2.z, g2.w}; }
            RG(0) RG(1) RG(2) RG(3) RG(4)
#undef RG
        }
        const v2f sv = {quad_sum(fmaf(sc.x, gR0.y, gR0.x)),
                        quad_sum(fmaf(sc.y, gR1.y, gR1.x))};
        l1 = vmax0(vfma(sigv, sv - bb, l1));
        if (q == 3) lam1_lds[r] = make_float2(l1.x, l1.y);
        __syncthreads();                                  // lam1 ready
        // --- col gather + primal prox prep (packed) ---
        v2f s2 = {0.f, 0.f};
        {
            const char* lb = (const char*)lam1_lds;
#define CG(K) if ((K) * 2 < cc) { const uint wv = ca[K];                       \
            s2 += *(const v2f*)(lb + (wv & 0xffffu));                          \
            s2 += *(const v2f*)(lb + (wv >> 16)); }
            CG(0) CG(1) CG(2) CG(3) CG(4) CG(5) CG(6) CG(7)
#undef CG
        }
        const v2f v = x - tauv * (s2 + l2);
        u  = (v + tauv) - z;
        A  = (z + z) - x;
        Bv = u + u;
        ab_lds[t] = make_float4(A.x, Bv.x, A.y, Bv.y);
        const v2f p = u * u;
        const float p0 = wave_sum_bcast(p.x);
        const float p1 = wave_sum_bcast(p.y);
        if ((t & 63) == 0) { atomicAdd(&red[it][0], p0); atomicAdd(&red[it][1], p1); }
        prev = it;
        __syncthreads();                                  // A/B + red ready
    }
    const float2 rr2 = *(const float2*)red[59];
    const v2f sc = {fmaxf(0.f, 1.f - c10 * rsqrtf(rr2.x)),
                    fmaxf(0.f, 1.f - c10 * rsqrtf(rr2.y))};
    const v2f xf = vfma(sc, u, z);
    out[r0 * NS + t] = xf.x;
    out[r1 * NS + t] = xf.y;
}

extern "C" void kernel_launch(void* const* d_in, const int* in_sizes, int n_in,
                              void* d_out, int out_size, void* d_ws, size_t ws_size,
                              hipStream_t stream)
{
    const float* X  = (const float*)d_in[0];
    const float* W1 = (const float*)d_in[1];
    const float* b1 = (const float*)d_in[2];
    const float* W2 = (const float*)d_in[3];
    const float* b2 = (const float*)d_in[4];
    const float* W3 = (const float*)d_in[5];
    const float* b3 = (const float*)d_in[6];
    const float* W4 = (const float*)d_in[7];
    const float* b4 = (const float*)d_in[8];
    const float* S  = (const float*)d_in[9];
    float* out = (float*)d_out;

    char* ws = (char*)d_ws;
    float* tau_ws    = (float*)(ws + 0);
    uint*  colmask_g = (uint*)(ws + 64);
    uint*  rowbits_g = (uint*)(ws + 8256);
    uint*  col_meta  = (uint*)(ws + 16448);
    uint*  col_cnt_g = (uint*)(ws + 32832);
    uint*  row_meta  = (uint*)(ws + 34880);
    uint*  row_cnt_g = (uint*)(ws + 51264);

    prep_scan<<<4, 512, 0, stream>>>(S, colmask_g, rowbits_g);
    prep_finish<<<1, 512, 0, stream>>>(colmask_g, rowbits_g, tau_ws,
                                       col_meta, col_cnt_g, row_meta, row_cnt_g);
    solve_kernel<<<BATCH / 2, 512, 0, stream>>>(X, W1, b1, W2, b2, W3, b3, W4, b4,
                                                tau_ws, col_meta, col_cnt_g,
                                                row_meta, row_cnt_g, out);
}